// Round 2
// baseline (405.143 us; speedup 1.0000x reference)
//
#include <hip/hip_runtime.h>
#include <stddef.h>

typedef _Float16 half8 __attribute__((ext_vector_type(8)));
typedef float floatx4 __attribute__((ext_vector_type(4)));
typedef float float4v __attribute__((ext_vector_type(4)));

#define NR 8192      // rows (fmap1)
#define MC 8192      // cols (fmap2 rows)
#define KD 256       // feature dim
#define BM 128
#define BN 128
#define BK 64
#define LOGIT_SCALE 0.0625f   // 1/sqrt(256)

// ---------------------------------------------------------------------------
// f32 -> f16 convert (both inputs) + zero rowsum accumulator
// 2048 blocks x 256 threads; each thread converts 8 elements.
// ---------------------------------------------------------------------------
__global__ void convert_kernel(const float* __restrict__ f1, const float* __restrict__ f2,
                               _Float16* __restrict__ h1, _Float16* __restrict__ h2,
                               float* __restrict__ rowsum) {
    int t = blockIdx.x * 256 + threadIdx.x;       // 0 .. 524287
    if (blockIdx.x < 32) rowsum[blockIdx.x * 256 + threadIdx.x] = 0.0f;
    int arr = t >> 18;                            // 262144 threads per array
    int idx = (t & 262143) * 8;
    const float* src = arr ? f2 : f1;
    _Float16* dst = arr ? h2 : h1;
    float4v a = *(const float4v*)(src + idx);
    float4v b = *(const float4v*)(src + idx + 4);
    half8 h;
    h[0] = (_Float16)a[0]; h[1] = (_Float16)a[1];
    h[2] = (_Float16)a[2]; h[3] = (_Float16)a[3];
    h[4] = (_Float16)b[0]; h[5] = (_Float16)b[1];
    h[6] = (_Float16)b[2]; h[7] = (_Float16)b[3];
    *(half8*)(dst + idx) = h;
}

// ---------------------------------------------------------------------------
// GEMM core: corr-tile = fmap1[tm*128 .. +128] . fmap2[tn*128 .. +128]^T / 16
// MODE 0: accumulate row-wise sum(exp(logit)) into rowsum[] via atomicAdd
// MODE 1: write exp(logit) * (1/rowsum[row]) to out[]
// 128x128 tile, BK=64, 4 waves (2x2), mfma_f32_16x16x32_f16, double-buffered
// LDS staged via global_load_lds(16B) with de-swizzled global source and
// XOR-swizzled ds_read (slot ^= row&7) for bank-conflict-free b128 (T2).
// ---------------------------------------------------------------------------
template <int MODE>
__launch_bounds__(256, 2)
__global__ void corr_gemm(const _Float16* __restrict__ A, const _Float16* __restrict__ B,
                          float* __restrict__ rowsum, float* __restrict__ out) {
    __shared__ __align__(16) _Float16 lds[2][2][BM * BK];  // [buf][matrix][128*64] = 64 KiB

    const int tid  = threadIdx.x;
    const int lane = tid & 63;
    const int wid  = tid >> 6;
    const int wr   = wid >> 1;          // wave row (0..1)  -> 64 rows
    const int wc   = wid & 1;           // wave col (0..1)  -> 64 cols

    // XCD-aware swizzle (4096 blocks, divisible by 8) then tm-major raster in
    // 8-wide tn groups: each XCD keeps a 512KB B-panel + streams A through L2.
    int bid = blockIdx.x;
    int swz = (bid & 7) * 512 + (bid >> 3);
    int group = swz >> 9;               // /512  == (bid&7)
    int rem   = swz & 511;
    int tn = group * 8 + (rem & 7);     // 0..63
    int tm = rem >> 3;                  // 0..63

    const _Float16* Abase = A + (size_t)(tm * BM) * KD;
    const _Float16* Bbase = B + (size_t)(tn * BN) * KD;

    // ---- staging: one BK-slab of A and B into lds[buf] ----
    // physical LDS layout is linear (global_load_lds writes base+lane*16B);
    // logical (row,kslot) lives at physical slot pslot = kslot ^ (row&7),
    // achieved by de-swizzling the per-lane GLOBAL source address (rule #21).
    auto stage = [&](int buf, int kt) {
#pragma unroll
        for (int m = 0; m < 2; ++m) {
            const _Float16* src = m ? Bbase : Abase;
            _Float16* lbase = &lds[buf][m][0];
#pragma unroll
            for (int i = 0; i < 4; ++i) {
                int L = i * 256 + tid;          // 0..1023 : 16B chunk index
                int row   = L >> 3;             // 0..127
                int pslot = L & 7;              // physical 16B slot in row
                int kslot = pslot ^ (row & 7);  // logical 16B slot (k/8)
                const _Float16* g = src + row * KD + kt * BK + kslot * 8;
                // wave-uniform LDS base; HW adds lane*16B
                _Float16* l = lbase + (size_t)(i * 256 + wid * 64) * 8;
                __builtin_amdgcn_global_load_lds(
                    (const __attribute__((address_space(1))) void*)g,
                    (__attribute__((address_space(3))) void*)l, 16, 0, 0);
            }
        }
    };

    floatx4 acc[4][4];
#pragma unroll
    for (int i = 0; i < 4; ++i)
#pragma unroll
        for (int j = 0; j < 4; ++j) acc[i][j] = floatx4{0.f, 0.f, 0.f, 0.f};

    stage(0, 0);
    __syncthreads();

    int cur = 0;
#pragma unroll
    for (int kt = 0; kt < 4; ++kt) {
        if (kt < 3) stage(cur ^ 1, kt + 1);

        const _Float16* la = &lds[cur][0][0];
        const _Float16* lb = &lds[cur][1][0];
#pragma unroll
        for (int kc = 0; kc < 2; ++kc) {
            half8 af[4], bf[4];
#pragma unroll
            for (int f = 0; f < 4; ++f) {
                int rowA = wr * 64 + f * 16 + (lane & 15);
                int ks   = kc * 4 + (lane >> 4);
                af[f] = *(const half8*)(la + rowA * 64 + ((ks ^ (rowA & 7)) * 8));
                int rowB = wc * 64 + f * 16 + (lane & 15);
                bf[f] = *(const half8*)(lb + rowB * 64 + ((ks ^ (rowB & 7)) * 8));
            }
#pragma unroll
            for (int i = 0; i < 4; ++i)
#pragma unroll
                for (int j = 0; j < 4; ++j)
                    acc[i][j] = __builtin_amdgcn_mfma_f32_16x16x32_f16(af[i], bf[j], acc[i][j], 0, 0, 0);
        }
        __syncthreads();   // drains prefetch (vmcnt0) + protects buffer reuse
        cur ^= 1;
    }

    // ---- epilogue ----
    // C/D layout (m89-verified): col = lane&15, row = (lane>>4)*4 + reg
    if (MODE == 0) {
#pragma unroll
        for (int i = 0; i < 4; ++i) {
#pragma unroll
            for (int r = 0; r < 4; ++r) {
                float s = 0.f;
#pragma unroll
                for (int j = 0; j < 4; ++j) s += __expf(acc[i][j][r] * LOGIT_SCALE);
                // butterfly over the 16 col-lanes (xor bits 0-3 preserve lane>>4)
                s += __shfl_xor(s, 1);
                s += __shfl_xor(s, 2);
                s += __shfl_xor(s, 4);
                s += __shfl_xor(s, 8);
                if ((lane & 15) == 0) {
                    int row = tm * BM + wr * 64 + i * 16 + (lane >> 4) * 4 + r;
                    atomicAdd(&rowsum[row], s);
                }
            }
        }
    } else {
#pragma unroll
        for (int i = 0; i < 4; ++i) {
#pragma unroll
            for (int r = 0; r < 4; ++r) {
                int row = tm * BM + wr * 64 + i * 16 + (lane >> 4) * 4 + r;
                float rinv = 1.0f / rowsum[row];
                float* orow = out + (size_t)row * MC + tn * BN + wc * 64 + (lane & 15);
#pragma unroll
                for (int j = 0; j < 4; ++j)
                    orow[j * 16] = __expf(acc[i][j][r] * LOGIT_SCALE) * rinv;
            }
        }
    }
}

// ---------------------------------------------------------------------------
extern "C" void kernel_launch(void* const* d_in, const int* in_sizes, int n_in,
                              void* d_out, int out_size, void* d_ws, size_t ws_size,
                              hipStream_t stream) {
    const float* f1 = (const float*)d_in[0];   // fmap1: 8192x256 f32
    const float* f2 = (const float*)d_in[1];   // fmap2: 8192x256 f32
    float* out = (float*)d_out;                // 8192x8192 f32

    // workspace layout: fmap1_h (4MB) | fmap2_h (4MB) | rowsum (32KB)
    _Float16* h1 = (_Float16*)d_ws;
    _Float16* h2 = h1 + (size_t)NR * KD;
    float* rowsum = (float*)(h2 + (size_t)MC * KD);

    convert_kernel<<<2048, 256, 0, stream>>>(f1, f2, h1, h2, rowsum);
    corr_gemm<0><<<4096, 256, 0, stream>>>(h1, h2, rowsum, nullptr);
    corr_gemm<1><<<4096, 256, 0, stream>>>(h1, h2, rowsum, out);
}

// Round 4
// 385.447 us; speedup vs baseline: 1.0511x; 1.0511x over previous
//
#include <hip/hip_runtime.h>
#include <stddef.h>

typedef _Float16 half8 __attribute__((ext_vector_type(8)));
typedef float floatx4 __attribute__((ext_vector_type(4)));
typedef float float4v __attribute__((ext_vector_type(4)));

#define NR 8192      // rows (fmap1)
#define MC 8192      // cols (fmap2 rows)
#define KD 256       // feature dim
#define BM 128
#define BN 128
#define BK 64
#define LOGIT_SCALE 0.0625f   // 1/sqrt(256)

// ---------------------------------------------------------------------------
// f32 -> f16 convert (both inputs) + zero rowsum accumulator
// ---------------------------------------------------------------------------
__global__ void convert_kernel(const float* __restrict__ f1, const float* __restrict__ f2,
                               _Float16* __restrict__ h1, _Float16* __restrict__ h2,
                               float* __restrict__ rowsum) {
    int t = blockIdx.x * 256 + threadIdx.x;       // 0 .. 524287
    if (blockIdx.x < 32) rowsum[blockIdx.x * 256 + threadIdx.x] = 0.0f;
    int arr = t >> 18;                            // 262144 threads per array
    int idx = (t & 262143) * 8;
    const float* src = arr ? f2 : f1;
    _Float16* dst = arr ? h2 : h1;
    float4v a = *(const float4v*)(src + idx);
    float4v b = *(const float4v*)(src + idx + 4);
    half8 h;
    h[0] = (_Float16)a[0]; h[1] = (_Float16)a[1];
    h[2] = (_Float16)a[2]; h[3] = (_Float16)a[3];
    h[4] = (_Float16)b[0]; h[5] = (_Float16)b[1];
    h[6] = (_Float16)b[2]; h[7] = (_Float16)b[3];
    *(half8*)(dst + idx) = h;
}

// ---------------------------------------------------------------------------
// m97-exact GEMM core (HW-verified structure: 874-912 TF @ 4096^3):
//   single-buffered LINEAR LDS (32 KiB -> 3 blocks/CU), per K-step:
//   stage(global_load_lds 16B) -> barrier -> ds_read_b128 + 32 MFMA -> barrier.
// No XOR swizzle (T2 is NULL at 2-barrier structures, m230), no manual dbuf
// (m99/m100: neutral; and prefetch-before-read forces conservative vmcnt(0)).
// MODE 0: accumulate row-wise sum(exp(logit)) into rowsum[] via atomicAdd
// MODE 1: write exp(logit) * (1/rowsum[row]) to out[]
// ---------------------------------------------------------------------------
template <int MODE>
__launch_bounds__(256, 3)
__global__ void corr_gemm(const _Float16* __restrict__ A, const _Float16* __restrict__ B,
                          float* __restrict__ rowsum, float* __restrict__ out) {
    __shared__ __align__(16) _Float16 As[BM * BK];   // 16 KiB
    __shared__ __align__(16) _Float16 Bs[BM * BK];   // 16 KiB

    const int tid  = threadIdx.x;
    const int lane = tid & 63;
    const int wid  = tid >> 6;
    const int wr   = wid >> 1;          // wave row (0..1)  -> 64 rows
    const int wc   = wid & 1;           // wave col (0..1)  -> 64 cols

    // XCD-aware swizzle (4096 blocks, divisible by 8); within an XCD: tn-inner
    // (8 wide) x tm-outer raster -> each XCD holds a 512 KB B-panel in L2.
    int bid = blockIdx.x;
    int swz = (bid & 7) * 512 + (bid >> 3);
    int tn = (swz >> 9) * 8 + (swz & 7);   // 0..63
    int tm = (swz & 511) >> 3;             // 0..63

    const _Float16* Abase = A + (size_t)(tm * BM) * KD;
    const _Float16* Bbase = B + (size_t)(tn * BN) * KD;

    floatx4 acc[4][4];
#pragma unroll
    for (int i = 0; i < 4; ++i)
#pragma unroll
        for (int j = 0; j < 4; ++j) acc[i][j] = floatx4{0.f, 0.f, 0.f, 0.f};

#pragma unroll
    for (int kt = 0; kt < 4; ++kt) {
        // ---- stage BK-slab of A and B (linear layout, 16B DMA chunks) ----
#pragma unroll
        for (int m = 0; m < 2; ++m) {
            const _Float16* src = m ? Bbase : Abase;
            _Float16* lbase = m ? &Bs[0] : &As[0];
#pragma unroll
            for (int i = 0; i < 4; ++i) {
                int L = i * 256 + tid;          // 0..1023 : 16B chunk index
                int row  = L >> 3;              // 0..127
                int slot = L & 7;               // 16B slot in row (k/8)
                const _Float16* g = src + row * KD + kt * BK + slot * 8;
                // wave-uniform LDS base; HW adds lane*16B -> chunk L at L*16B
                _Float16* l = lbase + (size_t)(i * 256 + wid * 64) * 8;
                __builtin_amdgcn_global_load_lds(
                    (const __attribute__((address_space(1))) void*)g,
                    (__attribute__((address_space(3))) void*)l, 16, 0, 0);
            }
        }
        __syncthreads();   // waits vmcnt(0): staged data visible

        // ---- compute: 2 x (8 ds_read_b128 + 16 MFMA) per wave ----
#pragma unroll
        for (int kc = 0; kc < 2; ++kc) {
            half8 af[4], bf[4];
#pragma unroll
            for (int f = 0; f < 4; ++f) {
                int rowA = wr * 64 + f * 16 + (lane & 15);
                int ks   = kc * 4 + (lane >> 4);
                af[f] = *(const half8*)(&As[rowA * BK + ks * 8]);
                int rowB = wc * 64 + f * 16 + (lane & 15);
                bf[f] = *(const half8*)(&Bs[rowB * BK + ks * 8]);
            }
#pragma unroll
            for (int i = 0; i < 4; ++i)
#pragma unroll
                for (int j = 0; j < 4; ++j)
                    acc[i][j] = __builtin_amdgcn_mfma_f32_16x16x32_f16(af[i], bf[j], acc[i][j], 0, 0, 0);
        }
        __syncthreads();   // protect LDS before next stage overwrites
    }

    // ---- epilogue ----
    // C/D layout (m89-verified): col = lane&15, row = (lane>>4)*4 + reg
    if (MODE == 0) {
#pragma unroll
        for (int i = 0; i < 4; ++i) {
#pragma unroll
            for (int r = 0; r < 4; ++r) {
                float s = 0.f;
#pragma unroll
                for (int j = 0; j < 4; ++j) s += __expf(acc[i][j][r] * LOGIT_SCALE);
                // butterfly over the 16 col-lanes (xor bits 0-3 keep lane>>4)
                s += __shfl_xor(s, 1);
                s += __shfl_xor(s, 2);
                s += __shfl_xor(s, 4);
                s += __shfl_xor(s, 8);
                if ((lane & 15) == 0) {
                    int row = tm * BM + wr * 64 + i * 16 + (lane >> 4) * 4 + r;
                    atomicAdd(&rowsum[row], s);
                }
            }
        }
    } else {
#pragma unroll
        for (int i = 0; i < 4; ++i) {
#pragma unroll
            for (int r = 0; r < 4; ++r) {
                int row = tm * BM + wr * 64 + i * 16 + (lane >> 4) * 4 + r;
                float rinv = 1.0f / rowsum[row];
                float* orow = out + (size_t)row * MC + tn * BN + wc * 64 + (lane & 15);
#pragma unroll
                for (int j = 0; j < 4; ++j)
                    orow[j * 16] = __expf(acc[i][j][r] * LOGIT_SCALE) * rinv;
            }
        }
    }
}

// ---------------------------------------------------------------------------
extern "C" void kernel_launch(void* const* d_in, const int* in_sizes, int n_in,
                              void* d_out, int out_size, void* d_ws, size_t ws_size,
                              hipStream_t stream) {
    const float* f1 = (const float*)d_in[0];   // fmap1: 8192x256 f32
    const float* f2 = (const float*)d_in[1];   // fmap2: 8192x256 f32
    float* out = (float*)d_out;                // 8192x8192 f32

    // workspace layout: fmap1_h (4MB) | fmap2_h (4MB) | rowsum (32KB)
    _Float16* h1 = (_Float16*)d_ws;
    _Float16* h2 = h1 + (size_t)NR * KD;
    float* rowsum = (float*)(h2 + (size_t)MC * KD);

    convert_kernel<<<2048, 256, 0, stream>>>(f1, f2, h1, h2, rowsum);
    corr_gemm<0><<<4096, 256, 0, stream>>>(h1, h2, rowsum, nullptr);
    corr_gemm<1><<<4096, 256, 0, stream>>>(h1, h2, rowsum, out);
}